// Round 1
// baseline (218.525 us; speedup 1.0000x reference)
//
#include <hip/hip_runtime.h>
#include <math.h>

#define T_GRID 2048
#define NC 2048
#define NT 2048
#define BATCH 16

// ---------- helpers: monotone float<->uint mapping for atomic min/max ----------
__device__ __forceinline__ unsigned mapf(float x) {
    unsigned b = __float_as_uint(x);
    return (b & 0x80000000u) ? ~b : (b | 0x80000000u);
}
__device__ __forceinline__ float unmapf(unsigned u) {
    return (u & 0x80000000u) ? __uint_as_float(u & 0x7fffffffu) : __uint_as_float(~u);
}

// ---------- K1: global min/max over xc and xt ----------
__global__ __launch_bounds__(256) void k_minmax(const float* __restrict__ xc,
                                                const float* __restrict__ xt,
                                                unsigned* __restrict__ mm) {
    int tid = blockIdx.x * blockDim.x + threadIdx.x;
    int stride = gridDim.x * blockDim.x;
    float lo = 3.4e38f, hi = -3.4e38f;
    for (int i = tid; i < BATCH * NC; i += stride) {
        float v = xc[i]; lo = fminf(lo, v); hi = fmaxf(hi, v);
    }
    for (int i = tid; i < BATCH * NT; i += stride) {
        float v = xt[i]; lo = fminf(lo, v); hi = fmaxf(hi, v);
    }
    // wave64 butterfly
    for (int off = 32; off; off >>= 1) {
        lo = fminf(lo, __shfl_down(lo, off));
        hi = fmaxf(hi, __shfl_down(hi, off));
    }
    __shared__ float slo[4], shi[4];
    int lane = threadIdx.x & 63, wv = threadIdx.x >> 6;
    if (lane == 0) { slo[wv] = lo; shi[wv] = hi; }
    __syncthreads();
    if (threadIdx.x == 0) {
        int nw = blockDim.x >> 6;
        for (int w = 1; w < nw; w++) { lo = fminf(lo, slo[w]); hi = fmaxf(hi, shi[w]); }
        atomicMin(&mm[0], mapf(lo));
        atomicMax(&mm[1], mapf(hi));
    }
}

// ---------- K2: h0,h1 = RBF(t, xc) @ [1, y], h1 normalized ----------
__global__ __launch_bounds__(256) void k_h(const float* __restrict__ xc,
                                           const float* __restrict__ yc,
                                           const float* __restrict__ ls_p,
                                           const float* __restrict__ os_p,
                                           const unsigned* __restrict__ mm,
                                           float* __restrict__ h0o,
                                           float* __restrict__ h1o) {
    int b = blockIdx.y;
    int i = blockIdx.x * 256 + threadIdx.x;
    float lower = unmapf(mm[0]), upper = unmapf(mm[1]);
    float step = (upper - lower) * (1.0f / (T_GRID - 1));
    float ls = ls_p[0], os = os_p[0];
    float c2 = -0.72134752044f / (ls * ls);   // -0.5*log2(e)/ls^2
    float t = fmaf((float)i, step, lower);

    __shared__ float2 sxy[256];
    const float* xb = xc + b * NC;
    const float* yb = yc + b * NC;
    float S0 = 0.f, S1 = 0.f;
    for (int j0 = 0; j0 < NC; j0 += 256) {
        __syncthreads();
        sxy[threadIdx.x] = make_float2(xb[j0 + threadIdx.x], yb[j0 + threadIdx.x]);
        __syncthreads();
#pragma unroll 8
        for (int j = 0; j < 256; j++) {
            float2 xy = sxy[j];
            float d = t - xy.x;
            float e = exp2f(d * d * c2);
            S0 += e;
            S1 = fmaf(e, xy.y, S1);
        }
    }
    float h0 = os * S0;
    float h1 = os * S1 / (h0 + 1e-8f);
    h0o[b * T_GRID + i] = h0;
    h1o[b * T_GRID + i] = h1;
}

// ---------- K3: fused 4-layer conv1d over the t-grid ----------
#define TILE 112
#define BW 132  // 128-position range + 2 pad each side

__global__ __launch_bounds__(128) void k_conv(const unsigned* __restrict__ mm,
                                              const float* __restrict__ h0a,
                                              const float* __restrict__ h1a,
                                              const float* __restrict__ w1, const float* __restrict__ b1,
                                              const float* __restrict__ w2, const float* __restrict__ b2,
                                              const float* __restrict__ w3, const float* __restrict__ b3,
                                              const float* __restrict__ w4, const float* __restrict__ b4,
                                              float* __restrict__ fmu, float* __restrict__ fsp) {
    __shared__ float rep[3][BW];
    __shared__ float L1[16][BW];
    __shared__ float L2[32][BW];
    __shared__ float L3[16][BW];
    __shared__ float w1L[15][16];
    __shared__ float w2L[80][32];
    __shared__ float w3L[160][16];
    __shared__ float w4L[80][2];
    __shared__ float bL[66];

    int tid = threadIdx.x;
    int b = blockIdx.y;
    int gstart = blockIdx.x * TILE - 8;

    float lower = unmapf(mm[0]), upper = unmapf(mm[1]);
    float step = (upper - lower) * (1.0f / (T_GRID - 1));

    // weights -> LDS, layout [i*5+k][o] (stride-1 over o => conflict-free)
    for (int idx = tid; idx < 240; idx += 128)  { int o = idx / 15,  r = idx % 15;  w1L[r][o] = w1[idx]; }
    for (int idx = tid; idx < 2560; idx += 128) { int o = idx / 80,  r = idx % 80;  w2L[r][o] = w2[idx]; }
    for (int idx = tid; idx < 2560; idx += 128) { int o = idx / 160, r = idx % 160; w3L[r][o] = w3[idx]; }
    for (int idx = tid; idx < 160; idx += 128)  { int o = idx / 80,  r = idx % 80;  w4L[r][o] = w4[idx]; }
    if (tid < 16) bL[tid] = b1[tid];
    if (tid < 32) bL[16 + tid] = b2[tid];
    if (tid < 16) bL[48 + tid] = b3[tid];
    if (tid < 2)  bL[64 + tid] = b4[tid];
    // zero the 4 pad columns
    if (tid < 4) {
        int c = (tid < 2) ? tid : tid + 128;
        for (int r = 0; r < 3; r++)  rep[r][c] = 0.f;
        for (int r = 0; r < 16; r++) { L1[r][c] = 0.f; L3[r][c] = 0.f; }
        for (int r = 0; r < 32; r++) L2[r][c] = 0.f;
    }
    // stage rep: channels (t, h0, h1); zero outside [0,T)
    {
        int p = tid, gp = gstart + p;
        bool valid = (gp >= 0 && gp < T_GRID);
        rep[0][p + 2] = valid ? fmaf((float)gp, step, lower) : 0.f;
        rep[1][p + 2] = valid ? h0a[b * T_GRID + gp] : 0.f;
        rep[2][p + 2] = valid ? h1a[b * T_GRID + gp] : 0.f;
    }
    __syncthreads();

    // ---- layer 1: 3 -> 16, relu. lanes: o = tid&15, strip of 16 positions ----
    {
        int o = tid & 15, s0 = (tid >> 4) << 4;
        float acc[16];
        float bias = bL[o];
#pragma unroll
        for (int s = 0; s < 16; s++) acc[s] = bias;
        for (int i = 0; i < 3; i++) {
            float x[20];
#pragma unroll
            for (int j = 0; j < 20; j++) x[j] = rep[i][s0 + j];
#pragma unroll
            for (int k = 0; k < 5; k++) {
                float w = w1L[i * 5 + k][o];
#pragma unroll
                for (int s = 0; s < 16; s++) acc[s] = fmaf(x[s + k], w, acc[s]);
            }
        }
#pragma unroll
        for (int s = 0; s < 16; s++) {
            int p = s0 + s, gp = gstart + p;
            bool valid = (p >= 2 && p < 126 && gp >= 0 && gp < T_GRID);
            L1[o][p + 2] = valid ? fmaxf(acc[s], 0.f) : 0.f;
        }
    }
    __syncthreads();

    // ---- layer 2: 16 -> 32, relu. lanes: o = tid&31, strip of 32 positions ----
    {
        int o = tid & 31, s0 = (tid >> 5) << 5;
        float acc[32];
        float bias = bL[16 + o];
#pragma unroll
        for (int s = 0; s < 32; s++) acc[s] = bias;
        for (int i = 0; i < 16; i++) {
            float x[36];
#pragma unroll
            for (int j = 0; j < 36; j++) x[j] = L1[i][s0 + j];
#pragma unroll
            for (int k = 0; k < 5; k++) {
                float w = w2L[i * 5 + k][o];
#pragma unroll
                for (int s = 0; s < 32; s++) acc[s] = fmaf(x[s + k], w, acc[s]);
            }
        }
#pragma unroll
        for (int s = 0; s < 32; s++) {
            int p = s0 + s, gp = gstart + p;
            bool valid = (p >= 4 && p < 124 && gp >= 0 && gp < T_GRID);
            L2[o][p + 2] = valid ? fmaxf(acc[s], 0.f) : 0.f;
        }
    }
    __syncthreads();

    // ---- layer 3: 32 -> 16, relu. lanes: o = tid&15, strip of 16 positions ----
    {
        int o = tid & 15, s0 = (tid >> 4) << 4;
        float acc[16];
        float bias = bL[48 + o];
#pragma unroll
        for (int s = 0; s < 16; s++) acc[s] = bias;
        for (int i = 0; i < 32; i++) {
            float x[20];
#pragma unroll
            for (int j = 0; j < 20; j++) x[j] = L2[i][s0 + j];
#pragma unroll
            for (int k = 0; k < 5; k++) {
                float w = w3L[i * 5 + k][o];
#pragma unroll
                for (int s = 0; s < 16; s++) acc[s] = fmaf(x[s + k], w, acc[s]);
            }
        }
#pragma unroll
        for (int s = 0; s < 16; s++) {
            int p = s0 + s, gp = gstart + p;
            bool valid = (p >= 6 && p < 122 && gp >= 0 && gp < T_GRID);
            L3[o][p + 2] = valid ? fmaxf(acc[s], 0.f) : 0.f;
        }
    }
    __syncthreads();

    // ---- layer 4: 16 -> 2 (no relu) + softplus epilogue; one position/thread ----
    {
        int p = tid, gp = gstart + p;
        float a0 = bL[64], a1 = bL[65];
        for (int i = 0; i < 16; i++) {
#pragma unroll
            for (int k = 0; k < 5; k++) {
                float x = L3[i][p + k];
                a0 = fmaf(x, w4L[i * 5 + k][0], a0);
                a1 = fmaf(x, w4L[i * 5 + k][1], a1);
            }
        }
        if (p >= 8 && p < 120 && gp >= 0 && gp < T_GRID) {
            float sp = fmaxf(a1, 0.f) + log1pf(expf(-fabsf(a1)));  // stable softplus
            fmu[b * T_GRID + gp] = a0;
            fsp[b * T_GRID + gp] = sp;
        }
    }
}

// ---------- K4: out = RBF(xt, t) @ [f_mu, softplus(f_sigma)] ----------
__global__ __launch_bounds__(256) void k_out(const float* __restrict__ xt,
                                             const float* __restrict__ ls_p,
                                             const float* __restrict__ os_p,
                                             const unsigned* __restrict__ mm,
                                             const float* __restrict__ fmu,
                                             const float* __restrict__ fsp,
                                             float2* __restrict__ out) {
    int b = blockIdx.y;
    int it = blockIdx.x * 256 + threadIdx.x;
    float lower = unmapf(mm[0]), upper = unmapf(mm[1]);
    float step = (upper - lower) * (1.0f / (T_GRID - 1));
    float ls = ls_p[0], os = os_p[0];
    float c2 = -0.72134752044f / (ls * ls);
    float x = xt[b * NT + it];

    __shared__ float2 sfs[256];
    const float* fm = fmu + b * T_GRID;
    const float* fs = fsp + b * T_GRID;
    float Smu = 0.f, Ssg = 0.f;
    for (int j0 = 0; j0 < T_GRID; j0 += 256) {
        __syncthreads();
        sfs[threadIdx.x] = make_float2(fm[j0 + threadIdx.x], fs[j0 + threadIdx.x]);
        __syncthreads();
        float d = x - fmaf((float)j0, step, lower);
#pragma unroll 8
        for (int j = 0; j < 256; j++) {
            float2 v = sfs[j];
            float e = exp2f(d * d * c2);
            Smu = fmaf(e, v.x, Smu);
            Ssg = fmaf(e, v.y, Ssg);
            d -= step;
        }
    }
    out[b * NT + it] = make_float2(os * Smu, os * Ssg);
}

// ---------- launcher ----------
extern "C" void kernel_launch(void* const* d_in, const int* in_sizes, int n_in,
                              void* d_out, int out_size, void* d_ws, size_t ws_size,
                              hipStream_t stream) {
    const float* xc = (const float*)d_in[0];
    const float* yc = (const float*)d_in[1];
    const float* xt = (const float*)d_in[2];
    const float* ls_psi = (const float*)d_in[3];
    const float* os_psi = (const float*)d_in[4];
    const float* ls_rho = (const float*)d_in[5];
    const float* os_rho = (const float*)d_in[6];
    const float* w1 = (const float*)d_in[7];
    const float* b1 = (const float*)d_in[8];
    const float* w2 = (const float*)d_in[9];
    const float* b2 = (const float*)d_in[10];
    const float* w3 = (const float*)d_in[11];
    const float* b3 = (const float*)d_in[12];
    const float* w4 = (const float*)d_in[13];
    const float* b4 = (const float*)d_in[14];

    char* ws = (char*)d_ws;
    unsigned* mm = (unsigned*)ws;                         // 2 uints at offset 0
    float* h0a = (float*)(ws + 64);
    float* h1a = (float*)(ws + 64 + 131072);
    float* fmu = (float*)(ws + 64 + 2 * 131072);
    float* fsp = (float*)(ws + 64 + 3 * 131072);

    // init atomic min/max slots: min <- 0xFFFFFFFF, max <- 0
    hipMemsetAsync(mm, 0xFF, 4, stream);
    hipMemsetAsync(mm + 1, 0x00, 4, stream);

    k_minmax<<<dim3(64), dim3(256), 0, stream>>>(xc, xt, mm);

    k_h<<<dim3(T_GRID / 256, BATCH), dim3(256), 0, stream>>>(xc, yc, ls_psi, os_psi, mm, h0a, h1a);

    int ntiles = (T_GRID + TILE - 1) / TILE;  // 19
    k_conv<<<dim3(ntiles, BATCH), dim3(128), 0, stream>>>(mm, h0a, h1a,
                                                          w1, b1, w2, b2, w3, b3, w4, b4,
                                                          fmu, fsp);

    k_out<<<dim3(NT / 256, BATCH), dim3(256), 0, stream>>>(xt, ls_rho, os_rho, mm, fmu, fsp,
                                                           (float2*)d_out);
}

// Round 2
// 148.645 us; speedup vs baseline: 1.4701x; 1.4701x over previous
//
#include <hip/hip_runtime.h>
#include <math.h>

#define T_GRID 2048
#define NC 2048
#define NT 2048
#define BATCH 16
#define NBINS 256
#define CAP 1536          // LDS float2 capacity for k_h chunking (12 KB)
#define XCUT 69.0f        // window cutoff: exp2(-0.72135*XCUT) ~ 2^-49.8

// ---------- helpers: monotone float<->uint mapping for atomic min/max ----------
__device__ __forceinline__ unsigned mapf(float x) {
    unsigned b = __float_as_uint(x);
    return (b & 0x80000000u) ? ~b : (b | 0x80000000u);
}
__device__ __forceinline__ float unmapf(unsigned u) {
    return (u & 0x80000000u) ? __uint_as_float(u & 0x7fffffffu) : __uint_as_float(~u);
}

// ---------- K1: global min/max over xc and xt ----------
__global__ __launch_bounds__(256) void k_minmax(const float* __restrict__ xc,
                                                const float* __restrict__ xt,
                                                unsigned* __restrict__ mm) {
    int tid = blockIdx.x * blockDim.x + threadIdx.x;
    int stride = gridDim.x * blockDim.x;
    float lo = 3.4e38f, hi = -3.4e38f;
    for (int i = tid; i < BATCH * NC; i += stride) {
        float v = xc[i]; lo = fminf(lo, v); hi = fmaxf(hi, v);
    }
    for (int i = tid; i < BATCH * NT; i += stride) {
        float v = xt[i]; lo = fminf(lo, v); hi = fmaxf(hi, v);
    }
    for (int off = 32; off; off >>= 1) {
        lo = fminf(lo, __shfl_down(lo, off));
        hi = fmaxf(hi, __shfl_down(hi, off));
    }
    __shared__ float slo[4], shi[4];
    int lane = threadIdx.x & 63, wv = threadIdx.x >> 6;
    if (lane == 0) { slo[wv] = lo; shi[wv] = hi; }
    __syncthreads();
    if (threadIdx.x == 0) {
        int nw = blockDim.x >> 6;
        for (int w = 1; w < nw; w++) { lo = fminf(lo, slo[w]); hi = fmaxf(hi, shi[w]); }
        atomicMin(&mm[0], mapf(lo));
        atomicMax(&mm[1], mapf(hi));
    }
}

// ---------- bin index helper ----------
__device__ __forceinline__ int bin_of(float v, float lower, float invbinw) {
    int b = (int)floorf((v - lower) * invbinw);
    return min(NBINS - 1, max(0, b));
}

// ---------- K2a: histogram of xc into NBINS per batch ----------
__global__ __launch_bounds__(256) void k_hist(const float* __restrict__ xc,
                                              const unsigned* __restrict__ mm,
                                              int* __restrict__ cnt) {
    int idx = blockIdx.x * 256 + threadIdx.x;           // 0 .. BATCH*NC-1
    float lower = unmapf(mm[0]), upper = unmapf(mm[1]);
    float invbinw = (float)NBINS / (upper - lower);
    int b = idx >> 11;                                   // / NC
    float x = xc[idx];
    atomicAdd(&cnt[b * NBINS + bin_of(x, lower, invbinw)], 1);
}

// ---------- K2b: per-batch exclusive scan; cnt is overwritten with starts (cursor) ----------
__global__ __launch_bounds__(NBINS) void k_scan(int* __restrict__ cnt,
                                                int* __restrict__ starts) {
    int b = blockIdx.x, tid = threadIdx.x;
    __shared__ int s[NBINS];
    int v = cnt[b * NBINS + tid];
    s[tid] = v;
    __syncthreads();
    for (int off = 1; off < NBINS; off <<= 1) {
        int t = (tid >= off) ? s[tid - off] : 0;
        __syncthreads();
        s[tid] += t;
        __syncthreads();
    }
    int excl = s[tid] - v;
    starts[b * (NBINS + 1) + tid] = excl;
    cnt[b * NBINS + tid] = excl;                         // becomes scatter cursor
    if (tid == NBINS - 1) starts[b * (NBINS + 1) + NBINS] = s[tid];
}

// ---------- K2c: scatter (x,y) into bin-sorted order ----------
__global__ __launch_bounds__(256) void k_scatter(const float* __restrict__ xc,
                                                 const float* __restrict__ yc,
                                                 const unsigned* __restrict__ mm,
                                                 int* __restrict__ cursor,
                                                 float2* __restrict__ sorted) {
    int idx = blockIdx.x * 256 + threadIdx.x;
    float lower = unmapf(mm[0]), upper = unmapf(mm[1]);
    float invbinw = (float)NBINS / (upper - lower);
    int b = idx >> 11;
    float x = xc[idx], y = yc[idx];
    int bin = bin_of(x, lower, invbinw);
    int pos = atomicAdd(&cursor[b * NBINS + bin], 1);
    sorted[b * NC + pos] = make_float2(x, y);
}

// ---------- K3: windowed h0,h1 = RBF(t, xc) @ [1, y], h1 normalized ----------
// block = 128 threads, one t-point each; grid (T_GRID/128, BATCH)
__global__ __launch_bounds__(128) void k_h(const float2* __restrict__ sorted,
                                           const int* __restrict__ starts,
                                           const float* __restrict__ ls_p,
                                           const float* __restrict__ os_p,
                                           const unsigned* __restrict__ mm,
                                           float* __restrict__ h0o,
                                           float* __restrict__ h1o) {
    __shared__ float2 sxy[CAP];
    int b = blockIdx.y;
    int i = blockIdx.x * 128 + threadIdx.x;
    float lower = unmapf(mm[0]), upper = unmapf(mm[1]);
    float step = (upper - lower) * (1.0f / (T_GRID - 1));
    float invbinw = (float)NBINS / (upper - lower);
    float ls = ls_p[0], os = os_p[0];
    float c2 = -0.72134752044f / (ls * ls);              // -0.5*log2(e)/ls^2
    float R = ls * sqrtf(XCUT);
    float t = fmaf((float)i, step, lower);

    const int* sb = starts + b * (NBINS + 1);
    const float2* srt = sorted + b * NC;

    // this thread's window
    int my_lo = sb[bin_of(t - R, lower, invbinw)];
    int my_hi = sb[bin_of(t + R, lower, invbinw) + 1];
    // block union window
    float t0 = fmaf((float)(blockIdx.x * 128), step, lower);
    float tL = t0 + 127.0f * step;
    int u_lo = sb[bin_of(t0 - R, lower, invbinw)];
    int u_hi = sb[bin_of(tL + R, lower, invbinw) + 1];

    float S0 = 0.f, S1 = 0.f;
    for (int base = u_lo; base < u_hi; base += CAP) {
        int n = min(CAP, u_hi - base);
        __syncthreads();
        for (int k = threadIdx.x; k < n; k += 128) sxy[k] = srt[base + k];
        __syncthreads();
        int a = max(my_lo, base) - base;
        int e = min(my_hi, base + n) - base;
        for (int j = a; j < e; j++) {
            float2 xy = sxy[j];
            float d = t - xy.x;
            float ev = exp2f(d * d * c2);
            S0 += ev;
            S1 = fmaf(ev, xy.y, S1);
        }
    }
    float h0 = os * S0;
    float h1 = os * S1 / (h0 + 1e-8f);
    h0o[b * T_GRID + i] = h0;
    h1o[b * T_GRID + i] = h1;
}

// ---------- K4: fused 4-layer conv1d over the t-grid (writes float2 f = (mu, softplus(sig))) ----------
#define TILE 112
#define BW 132

__global__ __launch_bounds__(128) void k_conv(const unsigned* __restrict__ mm,
                                              const float* __restrict__ h0a,
                                              const float* __restrict__ h1a,
                                              const float* __restrict__ w1, const float* __restrict__ b1,
                                              const float* __restrict__ w2, const float* __restrict__ b2,
                                              const float* __restrict__ w3, const float* __restrict__ b3,
                                              const float* __restrict__ w4, const float* __restrict__ b4,
                                              float2* __restrict__ f) {
    __shared__ float rep[3][BW];
    __shared__ float L1[16][BW];
    __shared__ float L2[32][BW];
    __shared__ float L3[16][BW];
    __shared__ float w1L[15][16];
    __shared__ float w2L[80][32];
    __shared__ float w3L[160][16];
    __shared__ float w4L[80][2];
    __shared__ float bL[66];

    int tid = threadIdx.x;
    int b = blockIdx.y;
    int gstart = blockIdx.x * TILE - 8;

    float lower = unmapf(mm[0]), upper = unmapf(mm[1]);
    float step = (upper - lower) * (1.0f / (T_GRID - 1));

    for (int idx = tid; idx < 240; idx += 128)  { int o = idx / 15,  r = idx % 15;  w1L[r][o] = w1[idx]; }
    for (int idx = tid; idx < 2560; idx += 128) { int o = idx / 80,  r = idx % 80;  w2L[r][o] = w2[idx]; }
    for (int idx = tid; idx < 2560; idx += 128) { int o = idx / 160, r = idx % 160; w3L[r][o] = w3[idx]; }
    for (int idx = tid; idx < 160; idx += 128)  { int o = idx / 80,  r = idx % 80;  w4L[r][o] = w4[idx]; }
    if (tid < 16) bL[tid] = b1[tid];
    if (tid < 32) bL[16 + tid] = b2[tid];
    if (tid < 16) bL[48 + tid] = b3[tid];
    if (tid < 2)  bL[64 + tid] = b4[tid];
    if (tid < 4) {
        int c = (tid < 2) ? tid : tid + 128;
        for (int r = 0; r < 3; r++)  rep[r][c] = 0.f;
        for (int r = 0; r < 16; r++) { L1[r][c] = 0.f; L3[r][c] = 0.f; }
        for (int r = 0; r < 32; r++) L2[r][c] = 0.f;
    }
    {
        int p = tid, gp = gstart + p;
        bool valid = (gp >= 0 && gp < T_GRID);
        rep[0][p + 2] = valid ? fmaf((float)gp, step, lower) : 0.f;
        rep[1][p + 2] = valid ? h0a[b * T_GRID + gp] : 0.f;
        rep[2][p + 2] = valid ? h1a[b * T_GRID + gp] : 0.f;
    }
    __syncthreads();

    {   // layer 1: 3 -> 16
        int o = tid & 15, s0 = (tid >> 4) << 4;
        float acc[16];
        float bias = bL[o];
#pragma unroll
        for (int s = 0; s < 16; s++) acc[s] = bias;
        for (int i = 0; i < 3; i++) {
            float x[20];
#pragma unroll
            for (int j = 0; j < 20; j++) x[j] = rep[i][s0 + j];
#pragma unroll
            for (int k = 0; k < 5; k++) {
                float w = w1L[i * 5 + k][o];
#pragma unroll
                for (int s = 0; s < 16; s++) acc[s] = fmaf(x[s + k], w, acc[s]);
            }
        }
#pragma unroll
        for (int s = 0; s < 16; s++) {
            int p = s0 + s, gp = gstart + p;
            bool valid = (p >= 2 && p < 126 && gp >= 0 && gp < T_GRID);
            L1[o][p + 2] = valid ? fmaxf(acc[s], 0.f) : 0.f;
        }
    }
    __syncthreads();

    {   // layer 2: 16 -> 32
        int o = tid & 31, s0 = (tid >> 5) << 5;
        float acc[32];
        float bias = bL[16 + o];
#pragma unroll
        for (int s = 0; s < 32; s++) acc[s] = bias;
        for (int i = 0; i < 16; i++) {
            float x[36];
#pragma unroll
            for (int j = 0; j < 36; j++) x[j] = L1[i][s0 + j];
#pragma unroll
            for (int k = 0; k < 5; k++) {
                float w = w2L[i * 5 + k][o];
#pragma unroll
                for (int s = 0; s < 32; s++) acc[s] = fmaf(x[s + k], w, acc[s]);
            }
        }
#pragma unroll
        for (int s = 0; s < 32; s++) {
            int p = s0 + s, gp = gstart + p;
            bool valid = (p >= 4 && p < 124 && gp >= 0 && gp < T_GRID);
            L2[o][p + 2] = valid ? fmaxf(acc[s], 0.f) : 0.f;
        }
    }
    __syncthreads();

    {   // layer 3: 32 -> 16
        int o = tid & 15, s0 = (tid >> 4) << 4;
        float acc[16];
        float bias = bL[48 + o];
#pragma unroll
        for (int s = 0; s < 16; s++) acc[s] = bias;
        for (int i = 0; i < 32; i++) {
            float x[20];
#pragma unroll
            for (int j = 0; j < 20; j++) x[j] = L2[i][s0 + j];
#pragma unroll
            for (int k = 0; k < 5; k++) {
                float w = w3L[i * 5 + k][o];
#pragma unroll
                for (int s = 0; s < 16; s++) acc[s] = fmaf(x[s + k], w, acc[s]);
            }
        }
#pragma unroll
        for (int s = 0; s < 16; s++) {
            int p = s0 + s, gp = gstart + p;
            bool valid = (p >= 6 && p < 122 && gp >= 0 && gp < T_GRID);
            L3[o][p + 2] = valid ? fmaxf(acc[s], 0.f) : 0.f;
        }
    }
    __syncthreads();

    {   // layer 4: 16 -> 2 + softplus epilogue
        int p = tid, gp = gstart + p;
        float a0 = bL[64], a1 = bL[65];
        for (int i = 0; i < 16; i++) {
#pragma unroll
            for (int k = 0; k < 5; k++) {
                float x = L3[i][p + k];
                a0 = fmaf(x, w4L[i * 5 + k][0], a0);
                a1 = fmaf(x, w4L[i * 5 + k][1], a1);
            }
        }
        if (p >= 8 && p < 120 && gp >= 0 && gp < T_GRID) {
            float sp = fmaxf(a1, 0.f) + log1pf(expf(-fabsf(a1)));
            f[b * T_GRID + gp] = make_float2(a0, sp);
        }
    }
}

// ---------- K5: windowed out = RBF(xt, t) @ [f_mu, f_sp] ----------
// block = 128 threads, one xt each; stages the whole batch f (16 KB) in LDS
__global__ __launch_bounds__(128) void k_out(const float* __restrict__ xt,
                                             const float* __restrict__ ls_p,
                                             const float* __restrict__ os_p,
                                             const unsigned* __restrict__ mm,
                                             const float2* __restrict__ f,
                                             float2* __restrict__ out) {
    __shared__ float2 sf[T_GRID];
    int b = blockIdx.y;
    int it = blockIdx.x * 128 + threadIdx.x;
    float lower = unmapf(mm[0]), upper = unmapf(mm[1]);
    float step = (upper - lower) * (1.0f / (T_GRID - 1));
    float invstep = 1.0f / step;
    float ls = ls_p[0], os = os_p[0];
    float c2 = -0.72134752044f / (ls * ls);
    float R = ls * sqrtf(XCUT);
    float x = xt[b * NT + it];

    const float2* fb = f + b * T_GRID;
    for (int k = threadIdx.x; k < T_GRID; k += 128) sf[k] = fb[k];
    __syncthreads();

    int j0 = max(0, (int)floorf((x - R - lower) * invstep));
    int j1 = min(T_GRID - 1, (int)ceilf((x + R - lower) * invstep));

    float Smu = 0.f, Ssg = 0.f;
    float d = x - fmaf((float)j0, step, lower);
    for (int j = j0; j <= j1; j++) {
        float2 v = sf[j];
        float e = exp2f(d * d * c2);
        Smu = fmaf(e, v.x, Smu);
        Ssg = fmaf(e, v.y, Ssg);
        d -= step;
    }
    out[b * NT + it] = make_float2(os * Smu, os * Ssg);
}

// ---------- launcher ----------
extern "C" void kernel_launch(void* const* d_in, const int* in_sizes, int n_in,
                              void* d_out, int out_size, void* d_ws, size_t ws_size,
                              hipStream_t stream) {
    const float* xc = (const float*)d_in[0];
    const float* yc = (const float*)d_in[1];
    const float* xt = (const float*)d_in[2];
    const float* ls_psi = (const float*)d_in[3];
    const float* os_psi = (const float*)d_in[4];
    const float* ls_rho = (const float*)d_in[5];
    const float* os_rho = (const float*)d_in[6];
    const float* w1 = (const float*)d_in[7];
    const float* b1 = (const float*)d_in[8];
    const float* w2 = (const float*)d_in[9];
    const float* b2 = (const float*)d_in[10];
    const float* w3 = (const float*)d_in[11];
    const float* b3 = (const float*)d_in[12];
    const float* w4 = (const float*)d_in[13];
    const float* b4 = (const float*)d_in[14];

    char* ws = (char*)d_ws;
    unsigned* mm = (unsigned*)ws;                        // 8 B
    int* cnt      = (int*)(ws + 1024);                   // 16 KB (also scatter cursor)
    int* starts   = (int*)(ws + 20480);                  // 16*257*4 = 16448 B
    float2* sorted= (float2*)(ws + 40960);               // 256 KB
    float* h0a    = (float*)(ws + 303104);               // 128 KB
    float* h1a    = (float*)(ws + 434176);               // 128 KB
    float2* f     = (float2*)(ws + 565248);              // 256 KB  (ends 827392)

    hipMemsetAsync(mm, 0xFF, 4, stream);                 // min slot
    hipMemsetAsync(mm + 1, 0x00, 4, stream);             // max slot
    hipMemsetAsync(cnt, 0, BATCH * NBINS * sizeof(int), stream);

    k_minmax<<<dim3(128), dim3(256), 0, stream>>>(xc, xt, mm);

    k_hist<<<dim3(BATCH * NC / 256), dim3(256), 0, stream>>>(xc, mm, cnt);
    k_scan<<<dim3(BATCH), dim3(NBINS), 0, stream>>>(cnt, starts);
    k_scatter<<<dim3(BATCH * NC / 256), dim3(256), 0, stream>>>(xc, yc, mm, cnt, sorted);

    k_h<<<dim3(T_GRID / 128, BATCH), dim3(128), 0, stream>>>(sorted, starts, ls_psi, os_psi,
                                                             mm, h0a, h1a);

    int ntiles = (T_GRID + TILE - 1) / TILE;             // 19
    k_conv<<<dim3(ntiles, BATCH), dim3(128), 0, stream>>>(mm, h0a, h1a,
                                                          w1, b1, w2, b2, w3, b3, w4, b4, f);

    k_out<<<dim3(NT / 128, BATCH), dim3(128), 0, stream>>>(xt, ls_rho, os_rho, mm, f,
                                                           (float2*)d_out);
}

// Round 3
// 124.005 us; speedup vs baseline: 1.7622x; 1.1987x over previous
//
#include <hip/hip_runtime.h>
#include <math.h>

#define T_GRID 2048
#define NC 2048
#define NT 2048
#define BATCH 16
#define NBINS 256
#define CAP2 1024          // LDS float2 staging capacity in conv h-phase (8 KB)
#define XCUT 28.0f         // window cutoff: exp2(-0.72135*28) ~ 2^-20.2 per point

__device__ __forceinline__ int bin_of(float v, float lower, float invbinw) {
    int b = (int)floorf((v - lower) * invbinw);
    return min(NBINS - 1, max(0, b));
}

// ---------- K1: single-block global min/max (no atomics, no init memset) ----------
__global__ __launch_bounds__(1024) void k_minmax(const float4* __restrict__ xc4,
                                                 const float4* __restrict__ xt4,
                                                 float* __restrict__ mm) {
    float lo = 3.4e38f, hi = -3.4e38f;
    for (int i = threadIdx.x; i < BATCH * NC / 4; i += 1024) {
        float4 v = xc4[i];
        lo = fminf(lo, fminf(fminf(v.x, v.y), fminf(v.z, v.w)));
        hi = fmaxf(hi, fmaxf(fmaxf(v.x, v.y), fmaxf(v.z, v.w)));
    }
    for (int i = threadIdx.x; i < BATCH * NT / 4; i += 1024) {
        float4 v = xt4[i];
        lo = fminf(lo, fminf(fminf(v.x, v.y), fminf(v.z, v.w)));
        hi = fmaxf(hi, fmaxf(fmaxf(v.x, v.y), fmaxf(v.z, v.w)));
    }
    for (int off = 32; off; off >>= 1) {
        lo = fminf(lo, __shfl_down(lo, off));
        hi = fmaxf(hi, __shfl_down(hi, off));
    }
    __shared__ float slo[16], shi[16];
    int lane = threadIdx.x & 63, wv = threadIdx.x >> 6;
    if (lane == 0) { slo[wv] = lo; shi[wv] = hi; }
    __syncthreads();
    if (threadIdx.x == 0) {
        for (int w = 1; w < 16; w++) { lo = fminf(lo, slo[w]); hi = fmaxf(hi, shi[w]); }
        mm[0] = lo; mm[1] = hi;
    }
}

// ---------- K2: per-batch bin sort (hist + scan + scatter in one block) ----------
__global__ __launch_bounds__(256) void k_binsort(const float* __restrict__ xc,
                                                 const float* __restrict__ yc,
                                                 const float* __restrict__ mm,
                                                 int* __restrict__ starts,
                                                 float2* __restrict__ sorted) {
    __shared__ int hist[NBINS];
    __shared__ int cur[NBINS];
    __shared__ int sc[NBINS];
    int b = blockIdx.x, tid = threadIdx.x;
    float lower = mm[0], upper = mm[1];
    float invbinw = (float)NBINS / (upper - lower);
    float xv[8], yv[8];
    int bn[8];
    hist[tid] = 0;
    __syncthreads();
#pragma unroll
    for (int k = 0; k < 8; k++) {
        int idx = tid + 256 * k;
        xv[k] = xc[b * NC + idx];
        yv[k] = yc[b * NC + idx];
        bn[k] = bin_of(xv[k], lower, invbinw);
        atomicAdd(&hist[bn[k]], 1);
    }
    __syncthreads();
    int v = hist[tid];
    sc[tid] = v;
    __syncthreads();
    for (int off = 1; off < NBINS; off <<= 1) {
        int t = (tid >= off) ? sc[tid - off] : 0;
        __syncthreads();
        sc[tid] += t;
        __syncthreads();
    }
    int excl = sc[tid] - v;
    starts[b * (NBINS + 1) + tid] = excl;
    cur[tid] = excl;
    if (tid == NBINS - 1) starts[b * (NBINS + 1) + NBINS] = sc[tid];
    __syncthreads();
#pragma unroll
    for (int k = 0; k < 8; k++) {
        int pos = atomicAdd(&cur[bn[k]], 1);
        sorted[b * NC + pos] = make_float2(xv[k], yv[k]);
    }
}

// ---------- K3: fused h-computation + 4-layer conv1d, one 112-position tile/block ----------
#define TILE 112
#define BW 132

__global__ __launch_bounds__(256) void k_conv(const float* __restrict__ mm,
                                              const float2* __restrict__ sorted,
                                              const int* __restrict__ starts,
                                              const float* __restrict__ ls_psi,
                                              const float* __restrict__ os_psi,
                                              const float* __restrict__ w1, const float* __restrict__ b1,
                                              const float* __restrict__ w2, const float* __restrict__ b2,
                                              const float* __restrict__ w3, const float* __restrict__ b3,
                                              const float* __restrict__ w4, const float* __restrict__ b4,
                                              float* __restrict__ f) {
    __shared__ float rep[3][BW];
    __shared__ float L1[16][BW];
    __shared__ float L2[32][BW];
    __shared__ float L3[16][BW];
    __shared__ float w1L[15][16];
    __shared__ float w2L[80][32];
    __shared__ float w3L[160][16];
    __shared__ float w4L[80][2];
    __shared__ float bL[66];
    __shared__ float2 sxy[CAP2];

    int tid = threadIdx.x;
    int b = blockIdx.y;
    int gstart = blockIdx.x * TILE - 8;

    float lower = mm[0], upper = mm[1];
    float step = (upper - lower) * (1.0f / (T_GRID - 1));
    float invbinw = (float)NBINS / (upper - lower);
    float ls = ls_psi[0], os = os_psi[0];
    float c2 = -0.72134752044f / (ls * ls);      // -0.5*log2(e)/ls^2
    float R = ls * sqrtf(XCUT);

    // ---- stage weights/biases, zero pad columns ----
    for (int idx = tid; idx < 240; idx += 256)  { int o = idx / 15,  r2 = idx % 15;  w1L[r2][o] = w1[idx]; }
    for (int idx = tid; idx < 2560; idx += 256) { int o = idx / 80,  r2 = idx % 80;  w2L[r2][o] = w2[idx]; }
    for (int idx = tid; idx < 2560; idx += 256) { int o = idx / 160, r2 = idx % 160; w3L[r2][o] = w3[idx]; }
    for (int idx = tid; idx < 160; idx += 256)  { int o = idx / 80,  r2 = idx % 80;  w4L[r2][o] = w4[idx]; }
    if (tid < 16) bL[tid] = b1[tid];
    if (tid < 32) bL[16 + tid] = b2[tid];
    if (tid < 16) bL[48 + tid] = b3[tid];
    if (tid < 2)  bL[64 + tid] = b4[tid];
    if (tid < 4) {
        int c = (tid < 2) ? tid : tid + 128;
        for (int r2 = 0; r2 < 3; r2++)  rep[r2][c] = 0.f;
        for (int r2 = 0; r2 < 16; r2++) { L1[r2][c] = 0.f; L3[r2][c] = 0.f; }
        for (int r2 = 0; r2 < 32; r2++) L2[r2][c] = 0.f;
    }

    // ---- phase 1: compute h for the tile's 128 positions (2 threads per position) ----
    {
        int p = tid & 127, r = tid >> 7;          // r in {0,1}: window-half split
        int gp = gstart + p;
        bool pvalid = (gp >= 0 && gp < T_GRID);
        float t = fmaf((float)gp, step, lower);
        const int* sb = starts + b * (NBINS + 1);
        const float2* srt = sorted + b * NC;
        int my_lo = 0, my_hi = 0;
        if (pvalid) {
            my_lo = sb[bin_of(t - R, lower, invbinw)];
            my_hi = sb[bin_of(t + R, lower, invbinw) + 1];
        }
        int g0 = max(gstart, 0), g1 = min(gstart + 127, T_GRID - 1);
        float tmin = fmaf((float)g0, step, lower) - R;
        float tmax = fmaf((float)g1, step, lower) + R;
        int u_lo = sb[bin_of(tmin, lower, invbinw)];
        int u_hi = sb[bin_of(tmax, lower, invbinw) + 1];

        float S0 = 0.f, S1 = 0.f;
        for (int base = u_lo; base < u_hi; base += CAP2) {
            int n = min(CAP2, u_hi - base);
            __syncthreads();
            for (int k = tid; k < n; k += 256) sxy[k] = srt[base + k];
            __syncthreads();
            int aa = max(my_lo, base) - base;
            int ee = min(my_hi, base + n) - base;
            for (int j = aa + r; j < ee; j += 2) {
                float2 xy = sxy[j];
                float d = t - xy.x;
                float ev = exp2f(d * d * c2);
                S0 += ev;
                S1 = fmaf(ev, xy.y, S1);
            }
        }
        __syncthreads();                           // sxy no longer read; reuse as partials
        float2* part = sxy;
        part[tid] = make_float2(S0, S1);
        __syncthreads();
        if (tid < 128) {
            float2 q = part[tid + 128];
            S0 += q.x; S1 += q.y;
            float h0 = os * S0;
            float h1 = os * S1 / (h0 + 1e-8f);
            rep[0][p + 2] = pvalid ? t : 0.f;
            rep[1][p + 2] = pvalid ? h0 : 0.f;
            rep[2][p + 2] = pvalid ? h1 : 0.f;
        }
    }
    __syncthreads();

    // ---- layer 1: 3 -> 16, relu. o=tid&15, 16 groups x 8 positions ----
    {
        int o = tid & 15, s0 = (tid >> 4) << 3;
        float acc[8];
        float bias = bL[o];
#pragma unroll
        for (int s = 0; s < 8; s++) acc[s] = bias;
        for (int i = 0; i < 3; i++) {
            float x[12];
#pragma unroll
            for (int j = 0; j < 12; j++) x[j] = rep[i][s0 + j];
#pragma unroll
            for (int k = 0; k < 5; k++) {
                float w = w1L[i * 5 + k][o];
#pragma unroll
                for (int s = 0; s < 8; s++) acc[s] = fmaf(x[s + k], w, acc[s]);
            }
        }
#pragma unroll
        for (int s = 0; s < 8; s++) {
            int p = s0 + s, gp = gstart + p;
            bool vv = (p >= 2 && p < 126 && gp >= 0 && gp < T_GRID);
            L1[o][p + 2] = vv ? fmaxf(acc[s], 0.f) : 0.f;
        }
    }
    __syncthreads();

    // ---- layer 2: 16 -> 32, relu. o=tid&31, 8 groups x 16 positions ----
    {
        int o = tid & 31, s0 = (tid >> 5) << 4;
        float acc[16];
        float bias = bL[16 + o];
#pragma unroll
        for (int s = 0; s < 16; s++) acc[s] = bias;
        for (int i = 0; i < 16; i++) {
            float x[20];
#pragma unroll
            for (int j = 0; j < 20; j++) x[j] = L1[i][s0 + j];
#pragma unroll
            for (int k = 0; k < 5; k++) {
                float w = w2L[i * 5 + k][o];
#pragma unroll
                for (int s = 0; s < 16; s++) acc[s] = fmaf(x[s + k], w, acc[s]);
            }
        }
#pragma unroll
        for (int s = 0; s < 16; s++) {
            int p = s0 + s, gp = gstart + p;
            bool vv = (p >= 4 && p < 124 && gp >= 0 && gp < T_GRID);
            L2[o][p + 2] = vv ? fmaxf(acc[s], 0.f) : 0.f;
        }
    }
    __syncthreads();

    // ---- layer 3: 32 -> 16, relu. o=tid&15, 16 groups x 8 positions ----
    {
        int o = tid & 15, s0 = (tid >> 4) << 3;
        float acc[8];
        float bias = bL[48 + o];
#pragma unroll
        for (int s = 0; s < 8; s++) acc[s] = bias;
        for (int i = 0; i < 32; i++) {
            float x[12];
#pragma unroll
            for (int j = 0; j < 12; j++) x[j] = L2[i][s0 + j];
#pragma unroll
            for (int k = 0; k < 5; k++) {
                float w = w3L[i * 5 + k][o];
#pragma unroll
                for (int s = 0; s < 8; s++) acc[s] = fmaf(x[s + k], w, acc[s]);
            }
        }
#pragma unroll
        for (int s = 0; s < 8; s++) {
            int p = s0 + s, gp = gstart + p;
            bool vv = (p >= 6 && p < 122 && gp >= 0 && gp < T_GRID);
            L3[o][p + 2] = vv ? fmaxf(acc[s], 0.f) : 0.f;
        }
    }
    __syncthreads();

    // ---- layer 4: 16 -> 2 + softplus. o=tid&1, one position per thread-pair ----
    {
        int o = tid & 1, p = tid >> 1;            // p in [0,128)
        float a = bL[64 + o];
        for (int i = 0; i < 16; i++) {
#pragma unroll
            for (int k = 0; k < 5; k++) {
                a = fmaf(L3[i][p + k], w4L[i * 5 + k][o], a);
            }
        }
        int gp = gstart + p;
        if (p >= 8 && p < 120 && gp >= 0 && gp < T_GRID) {
            if (o) {
                float sp = fmaxf(a, 0.f) + log1pf(expf(-fabsf(a)));
                f[2 * (b * T_GRID + gp) + 1] = sp;
            } else {
                f[2 * (b * T_GRID + gp)] = a;
            }
        }
    }
}

// ---------- K4: windowed out = RBF(xt, t) @ [f_mu, f_sp], 4 threads per xt ----------
__global__ __launch_bounds__(256) void k_out(const float* __restrict__ xt,
                                             const float* __restrict__ ls_rho,
                                             const float* __restrict__ os_rho,
                                             const float* __restrict__ mm,
                                             const float2* __restrict__ f,
                                             float2* __restrict__ out) {
    __shared__ float2 sf[T_GRID];
    __shared__ float2 part[256];
    int b = blockIdx.y, tid = threadIdx.x;
    int it = blockIdx.x * 64 + (tid & 63);
    int r = tid >> 6;                              // r in {0..3}: window quarter
    float lower = mm[0], upper = mm[1];
    float step = (upper - lower) * (1.0f / (T_GRID - 1));
    float invstep = 1.0f / step;
    float ls = ls_rho[0], os = os_rho[0];
    float c2 = -0.72134752044f / (ls * ls);
    float R = ls * sqrtf(XCUT);
    float x = xt[b * NT + it];

    const float2* fb = f + b * T_GRID;
    for (int k = tid; k < T_GRID; k += 256) sf[k] = fb[k];
    __syncthreads();

    int j0 = max(0, (int)floorf((x - R - lower) * invstep));
    int j1 = min(T_GRID - 1, (int)ceilf((x + R - lower) * invstep));

    float Smu = 0.f, Ssg = 0.f;
    float jf = (float)(j0 + r);
    for (int j = j0 + r; j <= j1; j += 4) {
        float2 v = sf[j];
        float d = x - fmaf(jf, step, lower);
        float e = exp2f(d * d * c2);
        Smu = fmaf(e, v.x, Smu);
        Ssg = fmaf(e, v.y, Ssg);
        jf += 4.0f;
    }
    part[tid] = make_float2(Smu, Ssg);
    __syncthreads();
    if (r == 0) {
#pragma unroll
        for (int q = 64; q < 256; q += 64) {
            float2 pp = part[tid + q];
            Smu += pp.x; Ssg += pp.y;
        }
        out[b * NT + it] = make_float2(os * Smu, os * Ssg);
    }
}

// ---------- launcher ----------
extern "C" void kernel_launch(void* const* d_in, const int* in_sizes, int n_in,
                              void* d_out, int out_size, void* d_ws, size_t ws_size,
                              hipStream_t stream) {
    const float* xc = (const float*)d_in[0];
    const float* yc = (const float*)d_in[1];
    const float* xt = (const float*)d_in[2];
    const float* ls_psi = (const float*)d_in[3];
    const float* os_psi = (const float*)d_in[4];
    const float* ls_rho = (const float*)d_in[5];
    const float* os_rho = (const float*)d_in[6];
    const float* w1 = (const float*)d_in[7];
    const float* b1 = (const float*)d_in[8];
    const float* w2 = (const float*)d_in[9];
    const float* b2 = (const float*)d_in[10];
    const float* w3 = (const float*)d_in[11];
    const float* b3 = (const float*)d_in[12];
    const float* w4 = (const float*)d_in[13];
    const float* b4 = (const float*)d_in[14];

    char* ws = (char*)d_ws;
    float* mm     = (float*)ws;                    // 8 B
    int* starts   = (int*)(ws + 64);               // 16*257*4 = 16448 B
    float2* sorted= (float2*)(ws + 16640);         // 256 KB
    float* f      = (float*)(ws + 278912);         // 256 KB (ends ~541 KB)

    k_minmax<<<dim3(1), dim3(1024), 0, stream>>>((const float4*)xc, (const float4*)xt, mm);

    k_binsort<<<dim3(BATCH), dim3(256), 0, stream>>>(xc, yc, mm, starts, sorted);

    int ntiles = (T_GRID + TILE - 1) / TILE;       // 19
    k_conv<<<dim3(ntiles, BATCH), dim3(256), 0, stream>>>(mm, sorted, starts,
                                                          ls_psi, os_psi,
                                                          w1, b1, w2, b2, w3, b3, w4, b4, f);

    k_out<<<dim3(NT / 64, BATCH), dim3(256), 0, stream>>>(xt, ls_rho, os_rho, mm,
                                                          (const float2*)f, (float2*)d_out);
}